// Round 2
// baseline (672.105 us; speedup 1.0000x reference)
//
#include <hip/hip_runtime.h>
#include <stdint.h>

#define DD 1024
#define BATCH 32768

typedef unsigned short u16;
typedef __attribute__((ext_vector_type(8))) __bf16 bf16x8;
typedef __attribute__((ext_vector_type(4))) float f32x4;
typedef __attribute__((ext_vector_type(4))) unsigned int u32x4;

__device__ __forceinline__ u16 f2bf(float x) {
  unsigned int u = __builtin_bit_cast(unsigned int, x);
  u = u + 0x7FFFu + ((u >> 16) & 1u);   // round-to-nearest-even
  return (u16)(u >> 16);
}

// One merged convert kernel: input (2048 blks), hidden (2048), 6 weights (64 each).
// Each block converts 4096 float4 (256 thr x 16).
__global__ void cvt_all(const float4* __restrict__ in0, const float4* __restrict__ in1,
                        const float4* __restrict__ w0, const float4* __restrict__ w1,
                        const float4* __restrict__ w2, const float4* __restrict__ w3,
                        const float4* __restrict__ w4, const float4* __restrict__ w5,
                        ushort4* __restrict__ o0, ushort4* __restrict__ o1,
                        ushort4* __restrict__ ow) {
  int b = blockIdx.x;
  const float4* s; ushort4* d; int rel;
  if (b < 2048)      { s = in0; d = o0; rel = b; }
  else if (b < 4096) { s = in1; d = o1; rel = b - 2048; }
  else {
    int t = b - 4096; int g = t >> 6; rel = t & 63;
    s = (g == 0) ? w0 : (g == 1) ? w1 : (g == 2) ? w2 : (g == 3) ? w3 : (g == 4) ? w4 : w5;
    d = ow + (size_t)g * 262144;
  }
  int i0 = rel * 4096 + threadIdx.x;
#pragma unroll
  for (int j = 0; j < 16; ++j) {
    int i = i0 + j * 256;
    float4 v = s[i];
    ushort4 o;
    o.x = f2bf(v.x); o.y = f2bf(v.y); o.z = f2bf(v.z); o.w = f2bf(v.w);
    d[i] = o;
  }
}

// ---------------- fused GRU GEMM, counted-vmcnt double-buffered pipeline -----
// Tile: BM=256, BN=64, BK=32. 512 thr = 8 waves (4M x 2N), wave tile 64x32.
// LDS per buffer (u16): A_in[256][32] @0, A_h[256][32] @8192, W[6][64][32] @16384+g*2048
// = 28672 u16 (56KB); two buffers = 112KB.
// Rows are 64B = 4x 16B slots; swizzle: slot' = slot ^ (row&3) (conflict-free b128).
#define BUF_U 28672

__device__ __forceinline__ bf16x8 ld8(const u16* p) {
  u32x4 v = *reinterpret_cast<const u32x4*>(p);
  return __builtin_bit_cast(bf16x8, v);
}

__device__ __forceinline__ f32x4 mfma16(bf16x8 a, bf16x8 b, f32x4 c) {
  return __builtin_amdgcn_mfma_f32_16x16x32_bf16(a, b, c, 0, 0, 0);
}

__device__ __forceinline__ void stage_one(const u16* src, const u16* dst) {
  __builtin_amdgcn_global_load_lds(
      (const __attribute__((address_space(1))) void*)src,
      (__attribute__((address_space(3))) void*)dst, 16, 0, 0);
}

__global__ __launch_bounds__(512, 2) void gru_fused(
    const u16* __restrict__ ain, const u16* __restrict__ ah,
    const u16* __restrict__ wall, const float* __restrict__ hidf,
    const float* __restrict__ b_ir, const float* __restrict__ b_hr,
    const float* __restrict__ b_iz, const float* __restrict__ b_hz,
    const float* __restrict__ b_in, const float* __restrict__ b_hn,
    float* __restrict__ out) {
  __shared__ __align__(16) u16 lds[2 * BUF_U];  // 112 KB -> 1 block/CU

  int bid = blockIdx.x;
  // XCD-bijective swizzle (2048 % 8 == 0), mb-fastest: consecutive wg on an XCD
  // share the same weight column-slice (L2-resident).
  int wg = ((bid & 7) << 8) | (bid >> 3);
  int nb = wg >> 7;    // 0..15   (64-col slice of D)
  int mb = wg & 127;   // 0..127  (256-row slice of batch)

  int tid = threadIdx.x;
  int wid = tid >> 6;
  int lane = tid & 63;
  int r15 = lane & 15;
  int kb = lane >> 4;
  int wm = wid >> 1;   // 0..3
  int wn = wid & 1;    // 0..1

  const f32x4 zero = {0.f, 0.f, 0.f, 0.f};
  f32x4 acc_r[4][2], acc_z[4][2], acc_n[4][2], acc_hn[4][2];
#pragma unroll
  for (int i = 0; i < 4; ++i)
#pragma unroll
    for (int j = 0; j < 2; ++j) {
      acc_r[i][j] = zero; acc_z[i][j] = zero;
      acc_n[i][j] = zero; acc_hn[i][j] = zero;
    }

  // Staging geometry: each chunk = 1KB = 16 rows x 64B; lane l -> row l>>2,
  // slot l&3; global k-slot pre-swizzled: (l&3) ^ ((l>>2)&3).
  int lrow = lane >> 2;
  unsigned koff = (unsigned)(((lane & 3) ^ (lrow & 3)) << 3);
  const u16* ain_r = ain + (unsigned)(mb * 256 + lrow) * DD + koff;
  const u16* ah_r  = ah  + (unsigned)(mb * 256 + lrow) * DD + koff;
  const u16* w_r   = wall + (unsigned)(nb * 64 + lrow) * DD + koff;
  int sub = wid & 3;          // W chunk-within-gate
  int g0 = wid >> 2;          // gates g0, g0+2, g0+4
  const u16* wsrc = w_r + (unsigned)(sub * 16) * DD;

  // 7 global_load_lds per thread per tile: 2x A_in, 2x A_h, 3x W.
  auto stage = [&](int kt, int bufb) {
    unsigned kc = (unsigned)(kt << 5);
    stage_one(ain_r + (unsigned)(wid * 16) * DD + kc,       &lds[bufb + wid * 512]);
    stage_one(ain_r + (unsigned)((wid + 8) * 16) * DD + kc, &lds[bufb + (wid + 8) * 512]);
    stage_one(ah_r  + (unsigned)(wid * 16) * DD + kc,       &lds[bufb + 8192 + wid * 512]);
    stage_one(ah_r  + (unsigned)((wid + 8) * 16) * DD + kc, &lds[bufb + 8192 + (wid + 8) * 512]);
    stage_one(wsrc + ((unsigned)g0 << 20) + kc,        &lds[bufb + 16384 + g0 * 2048 + sub * 512]);
    stage_one(wsrc + ((unsigned)(g0 + 2) << 20) + kc,  &lds[bufb + 16384 + (g0 + 2) * 2048 + sub * 512]);
    stage_one(wsrc + ((unsigned)(g0 + 4) << 20) + kc,  &lds[bufb + 16384 + (g0 + 4) * 2048 + sub * 512]);
  };

  auto compute = [&](int bufb) {
    const u16* B = &lds[bufb];
    bf16x8 afi[4], afh[4];
#pragma unroll
    for (int i = 0; i < 4; ++i) {
      int Rm = (wm << 6) + (i << 4) + r15;
      int sl = kb ^ (Rm & 3);
      afi[i] = ld8(B + Rm * 32 + sl * 8);
      afh[i] = ld8(B + 8192 + Rm * 32 + sl * 8);
    }
    __builtin_amdgcn_s_setprio(1);
#pragma unroll
    for (int jf = 0; jf < 2; ++jf) {
      int Rn = (wn << 5) + (jf << 4) + r15;
      int sl = kb ^ (Rn & 3);
      const u16* W0 = B + 16384 + Rn * 32 + sl * 8;
      bf16x8 bir = ld8(W0);
      bf16x8 bhr = ld8(W0 + 2048);
      bf16x8 biz = ld8(W0 + 4096);
      bf16x8 bhz = ld8(W0 + 6144);
      bf16x8 bin = ld8(W0 + 8192);
      bf16x8 bhn = ld8(W0 + 10240);
#pragma unroll
      for (int i = 0; i < 4; ++i) {
        acc_r[i][jf]  = mfma16(afi[i], bir, acc_r[i][jf]);
        acc_r[i][jf]  = mfma16(afh[i], bhr, acc_r[i][jf]);
        acc_z[i][jf]  = mfma16(afi[i], biz, acc_z[i][jf]);
        acc_z[i][jf]  = mfma16(afh[i], bhz, acc_z[i][jf]);
        acc_n[i][jf]  = mfma16(afi[i], bin, acc_n[i][jf]);
        acc_hn[i][jf] = mfma16(afh[i], bhn, acc_hn[i][jf]);
      }
    }
    __builtin_amdgcn_s_setprio(0);
  };

  stage(0, 0);
  for (int kt = 0; kt < 32; ++kt) {
    if (kt < 31) {
      stage(kt + 1, ((kt + 1) & 1) * BUF_U);
      // tile t's 7 loads complete; tile t+1's 7 stay in flight across the
      // barrier and the whole compute phase (T4: never drain to 0 mid-loop).
      asm volatile("s_waitcnt vmcnt(7)" ::: "memory");
    } else {
      asm volatile("s_waitcnt vmcnt(0)" ::: "memory");
    }
    __builtin_amdgcn_s_barrier();
    __builtin_amdgcn_sched_barrier(0);  // don't hoist ds_reads above the join
    compute((kt & 1) * BUF_U);
    asm volatile("s_waitcnt lgkmcnt(0)" ::: "memory");  // reads drained before release
    __builtin_amdgcn_s_barrier();
  }

  // ---- fused epilogue: gates + residual + dual store ----
  // C/D layout: col = lane&15, row = (lane>>4)*4 + q
#pragma unroll
  for (int jf = 0; jf < 2; ++jf) {
    int col = (nb << 6) + (wn << 5) + (jf << 4) + r15;
    float brc = b_ir[col] + b_hr[col];
    float bzc = b_iz[col] + b_hz[col];
    float bnc = b_in[col];
    float bhc = b_hn[col];
#pragma unroll
    for (int i = 0; i < 4; ++i) {
      int row0 = (mb << 8) + (wm << 6) + (i << 4) + (kb << 2);
#pragma unroll
      for (int q = 0; q < 4; ++q) {
        int row = row0 + q;
        float vr = acc_r[i][jf][q] + brc;
        float vz = acc_z[i][jf][q] + bzc;
        float vn = acc_n[i][jf][q] + bnc;
        float vh = acc_hn[i][jf][q] + bhc;
        float rg = __builtin_amdgcn_rcpf(1.f + __expf(-vr));
        float zg = __builtin_amdgcn_rcpf(1.f + __expf(-vz));
        float pre = vn + rg * vh;
        float ax = fabsf(pre);
        float e2 = __expf(-2.f * ax);
        float th = copysignf((1.f - e2) * __builtin_amdgcn_rcpf(1.f + e2), pre);
        float hp = hidf[((size_t)row << 10) + col];
        float h = (1.f - zg) * th + zg * hp;
        size_t o = ((size_t)row << 10) + col;
        out[o] = h;
        out[o + (size_t)BATCH * DD] = h;  // tuple (h, h)
      }
    }
  }
}

extern "C" void kernel_launch(void* const* d_in, const int* in_sizes, int n_in,
                              void* d_out, int out_size, void* d_ws, size_t ws_size,
                              hipStream_t stream) {
  (void)in_sizes; (void)n_in; (void)out_size; (void)ws_size;
  const float* inp = (const float*)d_in[0];
  const float* hid = (const float*)d_in[1];
  // ws: [input bf16 64MB][hidden bf16 64MB][W_ir..W_hn bf16 12MB]
  u16* ws_in  = (u16*)d_ws;
  u16* ws_hid = ws_in + (size_t)BATCH * DD;
  u16* ws_w   = ws_hid + (size_t)BATCH * DD;

  hipLaunchKernelGGL(cvt_all, dim3(4480), dim3(256), 0, stream,
                     (const float4*)inp, (const float4*)hid,
                     (const float4*)d_in[2], (const float4*)d_in[4],
                     (const float4*)d_in[6], (const float4*)d_in[8],
                     (const float4*)d_in[10], (const float4*)d_in[12],
                     (ushort4*)ws_in, (ushort4*)ws_hid, (ushort4*)ws_w);

  hipLaunchKernelGGL(gru_fused, dim3(2048), dim3(512), 0, stream,
                     ws_in, ws_hid, ws_w, hid,
                     (const float*)d_in[3], (const float*)d_in[5],
                     (const float*)d_in[7], (const float*)d_in[9],
                     (const float*)d_in[11], (const float*)d_in[13],
                     (float*)d_out);
}

// Round 3
// 643.242 us; speedup vs baseline: 1.0449x; 1.0449x over previous
//
#include <hip/hip_runtime.h>
#include <stdint.h>

#define DD 1024
#define BATCH 32768

typedef unsigned short u16;
typedef __attribute__((ext_vector_type(8))) __bf16 bf16x8;
typedef __attribute__((ext_vector_type(4))) float f32x4;
typedef __attribute__((ext_vector_type(4))) unsigned int u32x4;

__device__ __forceinline__ u16 f2bf(float x) {
  unsigned int u = __builtin_bit_cast(unsigned int, x);
  u = u + 0x7FFFu + ((u >> 16) & 1u);   // round-to-nearest-even
  return (u16)(u >> 16);
}

// One merged convert kernel: input (2048 blks), hidden (2048), 6 weights (64 each).
__global__ void cvt_all(const float4* __restrict__ in0, const float4* __restrict__ in1,
                        const float4* __restrict__ w0, const float4* __restrict__ w1,
                        const float4* __restrict__ w2, const float4* __restrict__ w3,
                        const float4* __restrict__ w4, const float4* __restrict__ w5,
                        ushort4* __restrict__ o0, ushort4* __restrict__ o1,
                        ushort4* __restrict__ ow) {
  int b = blockIdx.x;
  const float4* s; ushort4* d; int rel;
  if (b < 2048)      { s = in0; d = o0; rel = b; }
  else if (b < 4096) { s = in1; d = o1; rel = b - 2048; }
  else {
    int t = b - 4096; int g = t >> 6; rel = t & 63;
    s = (g == 0) ? w0 : (g == 1) ? w1 : (g == 2) ? w2 : (g == 3) ? w3 : (g == 4) ? w4 : w5;
    d = ow + (size_t)g * 262144;
  }
  int i0 = rel * 4096 + threadIdx.x;
#pragma unroll
  for (int j = 0; j < 16; ++j) {
    int i = i0 + j * 256;
    float4 v = s[i];
    ushort4 o;
    o.x = f2bf(v.x); o.y = f2bf(v.y); o.z = f2bf(v.z); o.w = f2bf(v.w);
    d[i] = o;
  }
}

// ---------------- fused GRU GEMM, counted-vmcnt dbuf + 2-phase interleave ----
// Tile: BM=256, BN=64, BK=32. 512 thr = 8 waves (4M x 2N), wave tile 64x32.
// LDS per buffer (u16): A_in[256][32] @0, A_h @8192, W[6][64][32] @16384+g*2048
// = 28672 u16 (56KB); two buffers = 112KB.
// Rows = 64B = 4x 16B slots. Bank arithmetic: bank_start(R,slot) =
// (16*(R&1) + 4*slot) mod 32, so the XOR source must be (R>>1)&3:
//   natural k-slot k of row R stored at slot  s = k ^ ((R>>1)&3).
// 16 consecutive rows at fixed kb then cover all 8 slot-starts exactly 2x
// (2 lanes/bank = free, m136). R1's (R&3) gave 4-way -> 4.19e7 conflicts.
#define BUF_U 28672

__device__ __forceinline__ bf16x8 ld8(const u16* p) {
  u32x4 v = *reinterpret_cast<const u32x4*>(p);
  return __builtin_bit_cast(bf16x8, v);
}

__device__ __forceinline__ f32x4 mfma16(bf16x8 a, bf16x8 b, f32x4 c) {
  return __builtin_amdgcn_mfma_f32_16x16x32_bf16(a, b, c, 0, 0, 0);
}

__device__ __forceinline__ void stage_one(const u16* src, const u16* dst) {
  __builtin_amdgcn_global_load_lds(
      (const __attribute__((address_space(1))) void*)src,
      (__attribute__((address_space(3))) void*)dst, 16, 0, 0);
}

__global__ __launch_bounds__(512, 2) void gru_fused(
    const u16* __restrict__ ain, const u16* __restrict__ ah,
    const u16* __restrict__ wall, const float* __restrict__ hidf,
    const float* __restrict__ b_ir, const float* __restrict__ b_hr,
    const float* __restrict__ b_iz, const float* __restrict__ b_hz,
    const float* __restrict__ b_in, const float* __restrict__ b_hn,
    float* __restrict__ out) {
  __shared__ __align__(16) u16 lds[2 * BUF_U];  // 112 KB -> 1 block/CU

  int bid = blockIdx.x;
  // XCD-bijective swizzle (2048 % 8 == 0), mb-fastest.
  int wg = ((bid & 7) << 8) | (bid >> 3);
  int nb = wg >> 7;    // 0..15   (64-col slice of D)
  int mb = wg & 127;   // 0..127  (256-row slice of batch)

  int tid = threadIdx.x;
  int wid = tid >> 6;
  int lane = tid & 63;
  int r15 = lane & 15;
  int kb = lane >> 4;
  int wm = wid >> 1;   // 0..3
  int wn = wid & 1;    // 0..1

  const f32x4 zero = {0.f, 0.f, 0.f, 0.f};
  f32x4 acc_r[4][2], acc_z[4][2], acc_n[4][2], acc_hn[4][2];
#pragma unroll
  for (int i = 0; i < 4; ++i)
#pragma unroll
    for (int j = 0; j < 2; ++j) {
      acc_r[i][j] = zero; acc_z[i][j] = zero;
      acc_n[i][j] = zero; acc_hn[i][j] = zero;
    }

  // Staging: chunk = 16 rows x 64B; lane l -> row l>>2, slot l&3; the global
  // k-slot fetched is pre-swizzled: (l&3) ^ ((l>>3)&3)  [= (l&3) ^ ((row>>1)&3)].
  int lrow = lane >> 2;
  unsigned koff = (unsigned)((((lane & 3) ^ ((lane >> 3) & 3))) << 3);
  const u16* ain_r = ain + (unsigned)(mb * 256 + lrow) * DD + koff;
  const u16* ah_r  = ah  + (unsigned)(mb * 256 + lrow) * DD + koff;
  const u16* w_r   = wall + (unsigned)(nb * 64 + lrow) * DD + koff;
  int sub = wid & 3;          // W chunk-within-gate
  int g0 = wid >> 2;          // gates g0, g0+2, g0+4
  const u16* wsrc = w_r + (unsigned)(sub * 16) * DD;

  // 7 global_load_lds per thread per tile: 2x A_in, 2x A_h, 3x W.
  auto stage = [&](int kt, int bufb) {
    unsigned kc = (unsigned)(kt << 5);
    stage_one(ain_r + (unsigned)(wid * 16) * DD + kc,       &lds[bufb + wid * 512]);
    stage_one(ain_r + (unsigned)((wid + 8) * 16) * DD + kc, &lds[bufb + (wid + 8) * 512]);
    stage_one(ah_r  + (unsigned)(wid * 16) * DD + kc,       &lds[bufb + 8192 + wid * 512]);
    stage_one(ah_r  + (unsigned)((wid + 8) * 16) * DD + kc, &lds[bufb + 8192 + (wid + 8) * 512]);
    stage_one(wsrc + ((unsigned)g0 << 20) + kc,        &lds[bufb + 16384 + g0 * 2048 + sub * 512]);
    stage_one(wsrc + ((unsigned)(g0 + 2) << 20) + kc,  &lds[bufb + 16384 + (g0 + 2) * 2048 + sub * 512]);
    stage_one(wsrc + ((unsigned)(g0 + 4) << 20) + kc,  &lds[bufb + 16384 + (g0 + 4) * 2048 + sub * 512]);
  };

  // Read-side swizzled slot: sl = kb ^ ((R>>1)&3); R mod 16 == r15 for both
  // A rows (wm*64 + i*16 + r15) and W rows (wn*32 + jf*16 + r15), so it is a
  // per-lane constant:
  int slsw = ((r15 >> 1) & 3);

  bf16x8 afi[4], afh[4], bw[6];

  stage(0, 0);
  for (int kt = 0; kt < 32; ++kt) {
    int bufb = (kt & 1) * BUF_U;
    if (kt < 31) {
      stage(kt + 1, ((kt + 1) & 1) * BUF_U);
      // tile kt's 7 loads (issued one full tile ago) complete; tile kt+1's 7
      // stay in flight across the whole compute (T4: never drain mid-loop).
      asm volatile("s_waitcnt vmcnt(7)" ::: "memory");
    } else {
      asm volatile("s_waitcnt vmcnt(0)" ::: "memory");
    }
    __builtin_amdgcn_s_barrier();          // buf[kt] fully written, all waves
    __builtin_amdgcn_sched_barrier(0);

    const u16* B = &lds[bufb];
    // ---- phase 1: A-frags + W(jf=0) reads, then 24 MFMA ----
#pragma unroll
    for (int i = 0; i < 4; ++i) {
      int Rm = (wm << 6) + (i << 4) + r15;
      int sl = kb ^ slsw;
      afi[i] = ld8(B + Rm * 32 + sl * 8);
      afh[i] = ld8(B + 8192 + Rm * 32 + sl * 8);
    }
    {
      int Rn = (wn << 5) + r15;
      int sl = kb ^ slsw;
      const u16* W0 = B + 16384 + Rn * 32 + sl * 8;
#pragma unroll
      for (int g = 0; g < 6; ++g) bw[g] = ld8(W0 + g * 2048);
    }
    asm volatile("s_waitcnt lgkmcnt(0)" ::: "memory");
    __builtin_amdgcn_sched_barrier(0);     // rule #18: keep MFMA below lgkm
    __builtin_amdgcn_s_setprio(1);
#pragma unroll
    for (int i = 0; i < 4; ++i) {
      acc_r[i][0]  = mfma16(afi[i], bw[0], acc_r[i][0]);
      acc_r[i][0]  = mfma16(afh[i], bw[1], acc_r[i][0]);
      acc_z[i][0]  = mfma16(afi[i], bw[2], acc_z[i][0]);
      acc_z[i][0]  = mfma16(afh[i], bw[3], acc_z[i][0]);
      acc_n[i][0]  = mfma16(afi[i], bw[4], acc_n[i][0]);
      acc_hn[i][0] = mfma16(afh[i], bw[5], acc_hn[i][0]);
    }
    __builtin_amdgcn_s_setprio(0);
    __builtin_amdgcn_s_barrier();          // phase lockstep
    __builtin_amdgcn_sched_barrier(0);

    // ---- phase 2: W(jf=1) reads, then 24 MFMA ----
    {
      int Rn = (wn << 5) + 16 + r15;
      int sl = kb ^ slsw;
      const u16* W0 = B + 16384 + Rn * 32 + sl * 8;
#pragma unroll
      for (int g = 0; g < 6; ++g) bw[g] = ld8(W0 + g * 2048);
    }
    asm volatile("s_waitcnt lgkmcnt(0)" ::: "memory");
    __builtin_amdgcn_sched_barrier(0);
    __builtin_amdgcn_s_setprio(1);
#pragma unroll
    for (int i = 0; i < 4; ++i) {
      acc_r[i][1]  = mfma16(afi[i], bw[0], acc_r[i][1]);
      acc_r[i][1]  = mfma16(afh[i], bw[1], acc_r[i][1]);
      acc_z[i][1]  = mfma16(afi[i], bw[2], acc_z[i][1]);
      acc_z[i][1]  = mfma16(afh[i], bw[3], acc_z[i][1]);
      acc_n[i][1]  = mfma16(afi[i], bw[4], acc_n[i][1]);
      acc_hn[i][1] = mfma16(afh[i], bw[5], acc_hn[i][1]);
    }
    __builtin_amdgcn_s_setprio(0);
    __builtin_amdgcn_s_barrier();          // all reads of buf[kt] drained
  }

  // ---- fused epilogue: gates + residual + dual store ----
  // C/D layout: col = lane&15, row = (lane>>4)*4 + q
#pragma unroll
  for (int jf = 0; jf < 2; ++jf) {
    int col = (nb << 6) + (wn << 5) + (jf << 4) + r15;
    float brc = b_ir[col] + b_hr[col];
    float bzc = b_iz[col] + b_hz[col];
    float bnc = b_in[col];
    float bhc = b_hn[col];
#pragma unroll
    for (int i = 0; i < 4; ++i) {
      int row0 = (mb << 8) + (wm << 6) + (i << 4) + (kb << 2);
#pragma unroll
      for (int q = 0; q < 4; ++q) {
        int row = row0 + q;
        float vr = acc_r[i][jf][q] + brc;
        float vz = acc_z[i][jf][q] + bzc;
        float vn = acc_n[i][jf][q] + bnc;
        float vh = acc_hn[i][jf][q] + bhc;
        float rg = __builtin_amdgcn_rcpf(1.f + __expf(-vr));
        float zg = __builtin_amdgcn_rcpf(1.f + __expf(-vz));
        float pre = vn + rg * vh;
        float ax = fabsf(pre);
        float e2 = __expf(-2.f * ax);
        float th = copysignf((1.f - e2) * __builtin_amdgcn_rcpf(1.f + e2), pre);
        float hp = hidf[((size_t)row << 10) + col];
        float h = (1.f - zg) * th + zg * hp;
        size_t o = ((size_t)row << 10) + col;
        out[o] = h;
        out[o + (size_t)BATCH * DD] = h;  // tuple (h, h)
      }
    }
  }
}

extern "C" void kernel_launch(void* const* d_in, const int* in_sizes, int n_in,
                              void* d_out, int out_size, void* d_ws, size_t ws_size,
                              hipStream_t stream) {
  (void)in_sizes; (void)n_in; (void)out_size; (void)ws_size;
  const float* inp = (const float*)d_in[0];
  const float* hid = (const float*)d_in[1];
  u16* ws_in  = (u16*)d_ws;
  u16* ws_hid = ws_in + (size_t)BATCH * DD;
  u16* ws_w   = ws_hid + (size_t)BATCH * DD;

  hipLaunchKernelGGL(cvt_all, dim3(4480), dim3(256), 0, stream,
                     (const float4*)inp, (const float4*)hid,
                     (const float4*)d_in[2], (const float4*)d_in[4],
                     (const float4*)d_in[6], (const float4*)d_in[8],
                     (const float4*)d_in[10], (const float4*)d_in[12],
                     (ushort4*)ws_in, (ushort4*)ws_hid, (ushort4*)ws_w);

  hipLaunchKernelGGL(gru_fused, dim3(2048), dim3(512), 0, stream,
                     ws_in, ws_hid, ws_w, hid,
                     (const float*)d_in[3], (const float*)d_in[5],
                     (const float*)d_in[7], (const float*)d_in[9],
                     (const float*)d_in[11], (const float*)d_in[13],
                     (float*)d_out);
}

// Round 4
// 582.345 us; speedup vs baseline: 1.1541x; 1.1046x over previous
//
#include <hip/hip_runtime.h>
#include <stdint.h>

#define DD 1024
#define BATCH 32768

typedef unsigned short u16;
typedef __attribute__((ext_vector_type(8))) __bf16 bf16x8;
typedef __attribute__((ext_vector_type(4))) float f32x4;
typedef __attribute__((ext_vector_type(4))) unsigned int u32x4;

__device__ __forceinline__ u16 f2bf(float x) {
  unsigned int u = __builtin_bit_cast(unsigned int, x);
  u = u + 0x7FFFu + ((u >> 16) & 1u);   // round-to-nearest-even
  return (u16)(u >> 16);
}

// One merged convert kernel: input (2048 blks), hidden (2048), 6 weights (64 each).
__global__ void cvt_all(const float4* __restrict__ in0, const float4* __restrict__ in1,
                        const float4* __restrict__ w0, const float4* __restrict__ w1,
                        const float4* __restrict__ w2, const float4* __restrict__ w3,
                        const float4* __restrict__ w4, const float4* __restrict__ w5,
                        ushort4* __restrict__ o0, ushort4* __restrict__ o1,
                        ushort4* __restrict__ ow) {
  int b = blockIdx.x;
  const float4* s; ushort4* d; int rel;
  if (b < 2048)      { s = in0; d = o0; rel = b; }
  else if (b < 4096) { s = in1; d = o1; rel = b - 2048; }
  else {
    int t = b - 4096; int g = t >> 6; rel = t & 63;
    s = (g == 0) ? w0 : (g == 1) ? w1 : (g == 2) ? w2 : (g == 3) ? w3 : (g == 4) ? w4 : w5;
    d = ow + (size_t)g * 262144;
  }
  int i0 = rel * 4096 + threadIdx.x;
#pragma unroll
  for (int j = 0; j < 16; ++j) {
    int i = i0 + j * 256;
    float4 v = s[i];
    ushort4 o;
    o.x = f2bf(v.x); o.y = f2bf(v.y); o.z = f2bf(v.z); o.w = f2bf(v.w);
    d[i] = o;
  }
}

// ---------------- fused GRU GEMM: A-dbuf + W-tribuf counted pipeline --------
// Tile: BM=256, BN=64, BK=32. 512 thr = 8 waves (4M x 2N), wave tile 64x32.
// LDS (u16): Abuf[2] x {A_in[256][32], A_h[256][32]} = 2x16384 @0
//            Wbuf[3] x {W[6][64][32]}                 = 3x12288 @32768
// Total 69632 u16 = 136 KB -> 1 block/CU, 8 waves.
// Swizzle (verified 0-conflict in R2): 64B rows, bank_start(R,slot) =
// (16*(R&1)+4*slot)%32 -> store natural k-slot k of row R at s = k^((R>>1)&3).
//
// Pipeline (per-wave issue order; vmcnt outstanding-count traced below):
//   prologue: A(0) W(0) A(1) W(1)
//   tile t:  [vmcnt; barrier]
//     phA: reads afi/afh/bw(jf0); lgkm(0); stage A(t+1) [t in 1..30]; MFMA x24
//     [barrier]
//     phB: reads bw(jf1);        lgkm(0); stage W(t+2) [t in 0..29]; MFMA x24
//   waits: t=0 -> vmcnt(7) (A1,W1 in flight); t in 1..30 -> vmcnt(3)
//   (W(t+1) in flight); t=31 -> vmcnt(0).
//   Cover: A(t) issued t-1 phA (~600 cyc, L2-hit ~250 ok);
//          W(t) issued t-2 phB (~1.5 tiles, L3 ~500 ok).
#define ABUF(b) ((b) * 16384)
#define WBUF(b) (32768 + (b) * 12288)

__device__ __forceinline__ bf16x8 ld8(const u16* p) {
  u32x4 v = *reinterpret_cast<const u32x4*>(p);
  return __builtin_bit_cast(bf16x8, v);
}

__device__ __forceinline__ f32x4 mfma16(bf16x8 a, bf16x8 b, f32x4 c) {
  return __builtin_amdgcn_mfma_f32_16x16x32_bf16(a, b, c, 0, 0, 0);
}

__device__ __forceinline__ void stage_one(const u16* src, const u16* dst) {
  __builtin_amdgcn_global_load_lds(
      (const __attribute__((address_space(1))) void*)src,
      (__attribute__((address_space(3))) void*)dst, 16, 0, 0);
}

__global__ __launch_bounds__(512, 2) void gru_fused(
    const u16* __restrict__ ain, const u16* __restrict__ ah,
    const u16* __restrict__ wall, const float* __restrict__ hidf,
    const float* __restrict__ b_ir, const float* __restrict__ b_hr,
    const float* __restrict__ b_iz, const float* __restrict__ b_hz,
    const float* __restrict__ b_in, const float* __restrict__ b_hn,
    float* __restrict__ out) {
  __shared__ __align__(16) u16 lds[69632];  // 136 KB

  int bid = blockIdx.x;
  // L2-locality mapping: XCD x owns mb range [x*16, x*16+16); within an XCD,
  // consecutive blocks sweep nb (16 blocks share one 1MB A-panel -> L2-hit).
  int x = bid & 7;
  int s = bid >> 3;           // 0..255
  int mb = (x << 4) | (s >> 4);  // 0..127
  int nb = s & 15;               // 0..15

  int tid = threadIdx.x;
  int wid = tid >> 6;
  int lane = tid & 63;
  int r15 = lane & 15;
  int kb = lane >> 4;
  int wm = wid >> 1;   // 0..3
  int wn = wid & 1;    // 0..1

  const f32x4 zero = {0.f, 0.f, 0.f, 0.f};
  f32x4 acc_r[4][2], acc_z[4][2], acc_n[4][2], acc_hn[4][2];
#pragma unroll
  for (int i = 0; i < 4; ++i)
#pragma unroll
    for (int j = 0; j < 2; ++j) {
      acc_r[i][j] = zero; acc_z[i][j] = zero;
      acc_n[i][j] = zero; acc_hn[i][j] = zero;
    }

  // Staging: chunk = 16 rows x 64B; lane l -> row l>>2, slot l&3; global
  // k-slot pre-swizzled: (l&3) ^ ((l>>3)&3) = (l&3) ^ ((row>>1)&3).
  int lrow = lane >> 2;
  unsigned koff = (unsigned)((((lane & 3) ^ ((lane >> 3) & 3))) << 3);
  const u16* ain_r = ain + (unsigned)(mb * 256 + lrow) * DD + koff;
  const u16* ah_r  = ah  + (unsigned)(mb * 256 + lrow) * DD + koff;
  const u16* w_r   = wall + (unsigned)(nb * 64 + lrow) * DD + koff;
  int sub = wid & 3;          // W chunk-within-gate (rows sub*16..)
  int g0 = wid >> 2;          // gates g0, g0+2, g0+4
  const u16* wsrc = w_r + (unsigned)(sub * 16) * DD;

  // 4 loads: A_in + A_h chunks {wid, wid+8} of tile kt1 -> Abuf[kt1&1]
  auto stageA = [&](int kt1) {
    unsigned kc = (unsigned)(kt1 << 5);
    int base = ABUF(kt1 & 1);
    stage_one(ain_r + (unsigned)(wid * 16) * DD + kc,       &lds[base + wid * 512]);
    stage_one(ain_r + (unsigned)((wid + 8) * 16) * DD + kc, &lds[base + (wid + 8) * 512]);
    stage_one(ah_r  + (unsigned)(wid * 16) * DD + kc,       &lds[base + 8192 + wid * 512]);
    stage_one(ah_r  + (unsigned)((wid + 8) * 16) * DD + kc, &lds[base + 8192 + (wid + 8) * 512]);
  };
  // 3 loads: W gates {g0, g0+2, g0+4}, row-chunk sub, of tile kt2 -> Wbuf[kt2%3]
  auto stageW = [&](int kt2, int wb) {
    unsigned kc = (unsigned)(kt2 << 5);
    int base = WBUF(wb);
    stage_one(wsrc + ((unsigned)g0 << 20) + kc,       &lds[base + g0 * 2048 + sub * 512]);
    stage_one(wsrc + ((unsigned)(g0 + 2) << 20) + kc, &lds[base + (g0 + 2) * 2048 + sub * 512]);
    stage_one(wsrc + ((unsigned)(g0 + 4) << 20) + kc, &lds[base + (g0 + 4) * 2048 + sub * 512]);
  };

  // Read-side swizzled slot: sl = kb ^ ((R>>1)&3), R mod 16 == r15 always.
  int slsw = ((r15 >> 1) & 3);
  int slx = (kb ^ slsw) << 3;

  bf16x8 afi[4], afh[4], bw[6];

  // prologue: 14 loads in flight
  stageA(0); stageW(0, 0); stageA(1); stageW(1, 1);

  int wcur = 0;    // kt % 3
  int wnx2 = 2;    // (kt+2) % 3
  for (int kt = 0; kt < 32; ++kt) {
    if (kt == 0) {
      asm volatile("s_waitcnt vmcnt(7)" ::: "memory");
    } else if (kt == 31) {
      asm volatile("s_waitcnt vmcnt(0)" ::: "memory");
    } else {
      asm volatile("s_waitcnt vmcnt(3)" ::: "memory");
    }
    __builtin_amdgcn_s_barrier();   // Abuf[kt&1] + Wbuf[wcur] globally ready
    __builtin_amdgcn_sched_barrier(0);

    const u16* BA = &lds[ABUF(kt & 1)];
    const u16* BW = &lds[WBUF(wcur)];

    // ---- phase A: A-frags + W(jf=0) reads -> stage A(kt+1) -> 24 MFMA ----
#pragma unroll
    for (int i = 0; i < 4; ++i) {
      int Rm = (wm << 6) + (i << 4) + r15;
      afi[i] = ld8(BA + Rm * 32 + slx);
      afh[i] = ld8(BA + 8192 + Rm * 32 + slx);
    }
    {
      int Rn = (wn << 5) + r15;
      const u16* W0 = BW + Rn * 32 + slx;
#pragma unroll
      for (int g = 0; g < 6; ++g) bw[g] = ld8(W0 + g * 2048);
    }
    asm volatile("s_waitcnt lgkmcnt(0)" ::: "memory");
    __builtin_amdgcn_sched_barrier(0);   // rule #18
    if (kt >= 1 && kt < 31) stageA(kt + 1);
    __builtin_amdgcn_s_setprio(1);
#pragma unroll
    for (int i = 0; i < 4; ++i) {
      acc_r[i][0]  = mfma16(afi[i], bw[0], acc_r[i][0]);
      acc_r[i][0]  = mfma16(afh[i], bw[1], acc_r[i][0]);
      acc_z[i][0]  = mfma16(afi[i], bw[2], acc_z[i][0]);
      acc_z[i][0]  = mfma16(afh[i], bw[3], acc_z[i][0]);
      acc_n[i][0]  = mfma16(afi[i], bw[4], acc_n[i][0]);
      acc_hn[i][0] = mfma16(afh[i], bw[5], acc_hn[i][0]);
    }
    __builtin_amdgcn_s_setprio(0);
    __builtin_amdgcn_s_barrier();
    __builtin_amdgcn_sched_barrier(0);

    // ---- phase B: W(jf=1) reads -> stage W(kt+2) -> 24 MFMA ----
    {
      int Rn = (wn << 5) + 16 + r15;
      const u16* W0 = BW + Rn * 32 + slx;
#pragma unroll
      for (int g = 0; g < 6; ++g) bw[g] = ld8(W0 + g * 2048);
    }
    asm volatile("s_waitcnt lgkmcnt(0)" ::: "memory");
    __builtin_amdgcn_sched_barrier(0);
    if (kt < 30) stageW(kt + 2, wnx2);
    __builtin_amdgcn_s_setprio(1);
#pragma unroll
    for (int i = 0; i < 4; ++i) {
      acc_r[i][1]  = mfma16(afi[i], bw[0], acc_r[i][1]);
      acc_r[i][1]  = mfma16(afh[i], bw[1], acc_r[i][1]);
      acc_z[i][1]  = mfma16(afi[i], bw[2], acc_z[i][1]);
      acc_z[i][1]  = mfma16(afh[i], bw[3], acc_z[i][1]);
      acc_n[i][1]  = mfma16(afi[i], bw[4], acc_n[i][1]);
      acc_hn[i][1] = mfma16(afh[i], bw[5], acc_hn[i][1]);
    }
    __builtin_amdgcn_s_setprio(0);
    // no end barrier: next tile's top vmcnt+barrier is the join
    wcur = (wcur == 2) ? 0 : wcur + 1;
    wnx2 = (wnx2 == 2) ? 0 : wnx2 + 1;
  }

  // ---- fused epilogue: gates + residual + dual store ----
  // C/D layout: col = lane&15, row = (lane>>4)*4 + q
#pragma unroll
  for (int jf = 0; jf < 2; ++jf) {
    int col = (nb << 6) + (wn << 5) + (jf << 4) + r15;
    float brc = b_ir[col] + b_hr[col];
    float bzc = b_iz[col] + b_hz[col];
    float bnc = b_in[col];
    float bhc = b_hn[col];
#pragma unroll
    for (int i = 0; i < 4; ++i) {
      int row0 = (mb << 8) + (wm << 6) + (i << 4) + (kb << 2);
#pragma unroll
      for (int q = 0; q < 4; ++q) {
        int row = row0 + q;
        float vr = acc_r[i][jf][q] + brc;
        float vz = acc_z[i][jf][q] + bzc;
        float vn = acc_n[i][jf][q] + bnc;
        float vh = acc_hn[i][jf][q] + bhc;
        float rg = __builtin_amdgcn_rcpf(1.f + __expf(-vr));
        float zg = __builtin_amdgcn_rcpf(1.f + __expf(-vz));
        float pre = vn + rg * vh;
        float ax = fabsf(pre);
        float e2 = __expf(-2.f * ax);
        float th = copysignf((1.f - e2) * __builtin_amdgcn_rcpf(1.f + e2), pre);
        float hp = hidf[((size_t)row << 10) + col];
        float h = (1.f - zg) * th + zg * hp;
        size_t o = ((size_t)row << 10) + col;
        out[o] = h;
        out[o + (size_t)BATCH * DD] = h;  // tuple (h, h)
      }
    }
  }
}

extern "C" void kernel_launch(void* const* d_in, const int* in_sizes, int n_in,
                              void* d_out, int out_size, void* d_ws, size_t ws_size,
                              hipStream_t stream) {
  (void)in_sizes; (void)n_in; (void)out_size; (void)ws_size;
  const float* inp = (const float*)d_in[0];
  const float* hid = (const float*)d_in[1];
  u16* ws_in  = (u16*)d_ws;
  u16* ws_hid = ws_in + (size_t)BATCH * DD;
  u16* ws_w   = ws_hid + (size_t)BATCH * DD;

  hipLaunchKernelGGL(cvt_all, dim3(4480), dim3(256), 0, stream,
                     (const float4*)inp, (const float4*)hid,
                     (const float4*)d_in[2], (const float4*)d_in[4],
                     (const float4*)d_in[6], (const float4*)d_in[8],
                     (const float4*)d_in[10], (const float4*)d_in[12],
                     (ushort4*)ws_in, (ushort4*)ws_hid, (ushort4*)ws_w);

  hipLaunchKernelGGL(gru_fused, dim3(2048), dim3(512), 0, stream,
                     ws_in, ws_hid, ws_w, hid,
                     (const float*)d_in[3], (const float*)d_in[5],
                     (const float*)d_in[7], (const float*)d_in[9],
                     (const float*)d_in[11], (const float*)d_in[13],
                     (float*)d_out);
}

// Round 5
// 577.891 us; speedup vs baseline: 1.1630x; 1.0077x over previous
//
#include <hip/hip_runtime.h>
#include <stdint.h>

#define DD 1024
#define BATCH 32768

typedef unsigned short u16;
typedef __attribute__((ext_vector_type(8))) __bf16 bf16x8;
typedef __attribute__((ext_vector_type(4))) float f32x4;
typedef __attribute__((ext_vector_type(4))) unsigned int u32x4;

__device__ __forceinline__ u16 f2bf(float x) {
  unsigned int u = __builtin_bit_cast(unsigned int, x);
  u = u + 0x7FFFu + ((u >> 16) & 1u);   // round-to-nearest-even
  return (u16)(u >> 16);
}

// One merged convert kernel: input (2048 blks), hidden (2048), 6 weights (64 each).
__global__ void cvt_all(const float4* __restrict__ in0, const float4* __restrict__ in1,
                        const float4* __restrict__ w0, const float4* __restrict__ w1,
                        const float4* __restrict__ w2, const float4* __restrict__ w3,
                        const float4* __restrict__ w4, const float4* __restrict__ w5,
                        ushort4* __restrict__ o0, ushort4* __restrict__ o1,
                        ushort4* __restrict__ ow) {
  int b = blockIdx.x;
  const float4* s; ushort4* d; int rel;
  if (b < 2048)      { s = in0; d = o0; rel = b; }
  else if (b < 4096) { s = in1; d = o1; rel = b - 2048; }
  else {
    int t = b - 4096; int g = t >> 6; rel = t & 63;
    s = (g == 0) ? w0 : (g == 1) ? w1 : (g == 2) ? w2 : (g == 3) ? w3 : (g == 4) ? w4 : w5;
    d = ow + (size_t)g * 262144;
  }
  int i0 = rel * 4096 + threadIdx.x;
#pragma unroll
  for (int j = 0; j < 16; ++j) {
    int i = i0 + j * 256;
    float4 v = s[i];
    ushort4 o;
    o.x = f2bf(v.x); o.y = f2bf(v.y); o.z = f2bf(v.z); o.w = f2bf(v.w);
    d[i] = o;
  }
}

// ------- fused GRU GEMM: A-dbuf + W-tribuf, m201-topology 4-phase tiles -----
// Tile: BM=256, BN=64, BK=32. 512 thr = 8 waves (4M x 2N), wave tile 64x32.
// LDS (u16): Abuf[2] x {A_in[256][32], A_h[256][32]} = 2x16384 @0
//            Wbuf[3] x {W[6][64][32]}                 = 3x12288 @32768  (136 KB)
// Swizzle (0-conflict, verified R2/R3): 64B rows; natural k-slot k of row R
// stored at slot k ^ ((R>>1)&3).
//
// Per tile, 4 phases of 12 MFMA, each phase (m201 order):
//   {ds_read subtile; stage 2-3 gloads; s_barrier; lgkmcnt(0); setprio1;
//    MFMA x12; setprio0}
// Read latency hides under the barrier wait; waves skew <1 phase -> LDS/MFMA
// pipe overlap. Counted vmcnt only at tile top.
//
// vmcnt ledger (per wave; A(t+1) issued t ph1/ph2, W(t+2) issued t ph3):
//   top of t (t=0..30): in flight [W(t):<=3, A(t):4, W(t+1):3] -> need A(t),W(t)
//   done -> vmcnt(3). Prologue issues A(0),W(0),W(1)=10 -> same invariant.
//   t=31: nothing newer than A(31),W(31) -> vmcnt(0).
#define ABUF(b) ((b) * 16384)
#define WBUF(b) (32768 + (b) * 12288)

__device__ __forceinline__ bf16x8 ld8(const u16* p) {
  u32x4 v = *reinterpret_cast<const u32x4*>(p);
  return __builtin_bit_cast(bf16x8, v);
}

__device__ __forceinline__ f32x4 mfma16(bf16x8 a, bf16x8 b, f32x4 c) {
  return __builtin_amdgcn_mfma_f32_16x16x32_bf16(a, b, c, 0, 0, 0);
}

__device__ __forceinline__ void stage_one(const u16* src, const u16* dst) {
  __builtin_amdgcn_global_load_lds(
      (const __attribute__((address_space(1))) void*)src,
      (__attribute__((address_space(3))) void*)dst, 16, 0, 0);
}

__global__ __launch_bounds__(512, 2) void gru_fused(
    const u16* __restrict__ ain, const u16* __restrict__ ah,
    const u16* __restrict__ wall, const float* __restrict__ hidf,
    const float* __restrict__ b_ir, const float* __restrict__ b_hr,
    const float* __restrict__ b_iz, const float* __restrict__ b_hz,
    const float* __restrict__ b_in, const float* __restrict__ b_hn,
    float* __restrict__ out) {
  __shared__ __align__(16) u16 lds[69632];  // 136 KB

  int bid = blockIdx.x;
  // L2-locality mapping: XCD x owns mb range [x*16, x*16+16); 16 consecutive
  // blocks of an XCD share one 1MB A-panel (L2-resident).
  int x = bid & 7;
  int s = bid >> 3;              // 0..255
  int mb = (x << 4) | (s >> 4);  // 0..127
  int nb = s & 15;               // 0..15

  int tid = threadIdx.x;
  int wid = tid >> 6;
  int lane = tid & 63;
  int r15 = lane & 15;
  int kb = lane >> 4;
  int wm = wid >> 1;   // 0..3
  int wn = wid & 1;    // 0..1

  const f32x4 zero = {0.f, 0.f, 0.f, 0.f};
  f32x4 acc_r[4][2], acc_z[4][2], acc_n[4][2], acc_hn[4][2];
#pragma unroll
  for (int i = 0; i < 4; ++i)
#pragma unroll
    for (int j = 0; j < 2; ++j) {
      acc_r[i][j] = zero; acc_z[i][j] = zero;
      acc_n[i][j] = zero; acc_hn[i][j] = zero;
    }

  // Staging: chunk = 16 rows x 64B; lane l -> row l>>2, slot l&3; global
  // k-slot pre-swizzled: (l&3) ^ ((l>>3)&3) = (l&3) ^ ((row>>1)&3).
  int lrow = lane >> 2;
  unsigned koff = (unsigned)((((lane & 3) ^ ((lane >> 3) & 3))) << 3);
  const u16* ain_r = ain + (unsigned)(mb * 256 + lrow) * DD + koff;
  const u16* ah_r  = ah  + (unsigned)(mb * 256 + lrow) * DD + koff;
  const u16* w_r   = wall + (unsigned)(nb * 64 + lrow) * DD + koff;
  int sub = wid & 3;          // W chunk-within-gate (rows sub*16..)
  int g0 = wid >> 2;          // gates g0, g0+2, g0+4
  const u16* wsrc = w_r + (unsigned)(sub * 16) * DD;

  auto stageAin = [&](int kt1) {   // 2 gloads
    unsigned kc = (unsigned)(kt1 << 5);
    int base = ABUF(kt1 & 1);
    stage_one(ain_r + (unsigned)(wid * 16) * DD + kc,       &lds[base + wid * 512]);
    stage_one(ain_r + (unsigned)((wid + 8) * 16) * DD + kc, &lds[base + (wid + 8) * 512]);
  };
  auto stageAh = [&](int kt1) {    // 2 gloads
    unsigned kc = (unsigned)(kt1 << 5);
    int base = ABUF(kt1 & 1);
    stage_one(ah_r + (unsigned)(wid * 16) * DD + kc,       &lds[base + 8192 + wid * 512]);
    stage_one(ah_r + (unsigned)((wid + 8) * 16) * DD + kc, &lds[base + 8192 + (wid + 8) * 512]);
  };
  auto stageW = [&](int kt2, int wb) {  // 3 gloads
    unsigned kc = (unsigned)(kt2 << 5);
    int base = WBUF(wb);
    stage_one(wsrc + ((unsigned)g0 << 20) + kc,       &lds[base + g0 * 2048 + sub * 512]);
    stage_one(wsrc + ((unsigned)(g0 + 2) << 20) + kc, &lds[base + (g0 + 2) * 2048 + sub * 512]);
    stage_one(wsrc + ((unsigned)(g0 + 4) << 20) + kc, &lds[base + (g0 + 4) * 2048 + sub * 512]);
  };

  // Read-side swizzled slot: sl = kb ^ ((R>>1)&3); R mod 16 == r15 always.
  int slx = ((kb ^ ((r15 >> 1) & 3))) << 3;

  bf16x8 afi[4], afh[4], bwA[3], bwB[3];

  // prologue: A(0), W(0), W(1) = 10 loads in flight
  stageAin(0); stageAh(0); stageW(0, 0); stageW(1, 1);

  int wcur = 0;    // kt % 3
  int wnx2 = 2;    // (kt+2) % 3
  for (int kt = 0; kt < 32; ++kt) {
    if (kt == 31) {
      asm volatile("s_waitcnt vmcnt(0)" ::: "memory");
    } else {
      asm volatile("s_waitcnt vmcnt(3)" ::: "memory");
    }
    __builtin_amdgcn_s_barrier();   // Abuf[kt&1] + Wbuf[wcur] globally ready
    __builtin_amdgcn_sched_barrier(0);

    const u16* BA = &lds[ABUF(kt & 1)];
    const u16* BW = &lds[WBUF(wcur)];
    const u16* W0 = BW + ((wn << 5) + r15) * 32 + slx;        // jf=0 rows
    const u16* W1 = BW + ((wn << 5) + 16 + r15) * 32 + slx;   // jf=1 rows

    // ---- ph1: A-frags + W(jf0,g012); stage A_in(t+1); MFMA r/z-i (jf0) ----
#pragma unroll
    for (int i = 0; i < 4; ++i) {
      int Rm = (wm << 6) + (i << 4) + r15;
      afi[i] = ld8(BA + Rm * 32 + slx);
      afh[i] = ld8(BA + 8192 + Rm * 32 + slx);
    }
    bwA[0] = ld8(W0);            // ir
    bwA[1] = ld8(W0 + 2048);     // hr
    bwA[2] = ld8(W0 + 4096);     // iz
    if (kt < 31) stageAin(kt + 1);
    __builtin_amdgcn_s_barrier();
    asm volatile("s_waitcnt lgkmcnt(0)" ::: "memory");
    __builtin_amdgcn_sched_barrier(0);
    __builtin_amdgcn_s_setprio(1);
#pragma unroll
    for (int i = 0; i < 4; ++i) {
      acc_r[i][0] = mfma16(afi[i], bwA[0], acc_r[i][0]);
      acc_r[i][0] = mfma16(afh[i], bwA[1], acc_r[i][0]);
      acc_z[i][0] = mfma16(afi[i], bwA[2], acc_z[i][0]);
    }
    __builtin_amdgcn_s_setprio(0);

    // ---- ph2: W(jf0,g345); stage A_h(t+1); MFMA z-h/n/hn (jf0) ----
    bwB[0] = ld8(W0 + 6144);     // hz
    bwB[1] = ld8(W0 + 8192);     // in
    bwB[2] = ld8(W0 + 10240);    // hn
    if (kt < 31) stageAh(kt + 1);
    __builtin_amdgcn_s_barrier();
    asm volatile("s_waitcnt lgkmcnt(0)" ::: "memory");
    __builtin_amdgcn_sched_barrier(0);
    __builtin_amdgcn_s_setprio(1);
#pragma unroll
    for (int i = 0; i < 4; ++i) {
      acc_z[i][0]  = mfma16(afh[i], bwB[0], acc_z[i][0]);
      acc_n[i][0]  = mfma16(afi[i], bwB[1], acc_n[i][0]);
      acc_hn[i][0] = mfma16(afh[i], bwB[2], acc_hn[i][0]);
    }
    __builtin_amdgcn_s_setprio(0);

    // ---- ph3: W(jf1,g012); stage W(t+2); MFMA r/z-i (jf1) ----
    bwA[0] = ld8(W1);
    bwA[1] = ld8(W1 + 2048);
    bwA[2] = ld8(W1 + 4096);
    if (kt < 30) stageW(kt + 2, wnx2);
    __builtin_amdgcn_s_barrier();
    asm volatile("s_waitcnt lgkmcnt(0)" ::: "memory");
    __builtin_amdgcn_sched_barrier(0);
    __builtin_amdgcn_s_setprio(1);
#pragma unroll
    for (int i = 0; i < 4; ++i) {
      acc_r[i][1] = mfma16(afi[i], bwA[0], acc_r[i][1]);
      acc_r[i][1] = mfma16(afh[i], bwA[1], acc_r[i][1]);
      acc_z[i][1] = mfma16(afi[i], bwA[2], acc_z[i][1]);
    }
    __builtin_amdgcn_s_setprio(0);

    // ---- ph4: W(jf1,g345); MFMA z-h/n/hn (jf1) ----
    bwB[0] = ld8(W1 + 6144);
    bwB[1] = ld8(W1 + 8192);
    bwB[2] = ld8(W1 + 10240);
    __builtin_amdgcn_s_barrier();
    asm volatile("s_waitcnt lgkmcnt(0)" ::: "memory");
    __builtin_amdgcn_sched_barrier(0);
    __builtin_amdgcn_s_setprio(1);
#pragma unroll
    for (int i = 0; i < 4; ++i) {
      acc_z[i][1]  = mfma16(afh[i], bwB[0], acc_z[i][1]);
      acc_n[i][1]  = mfma16(afi[i], bwB[1], acc_n[i][1]);
      acc_hn[i][1] = mfma16(afh[i], bwB[2], acc_hn[i][1]);
    }
    __builtin_amdgcn_s_setprio(0);

    wcur = (wcur == 2) ? 0 : wcur + 1;
    wnx2 = (wnx2 == 2) ? 0 : wnx2 + 1;
  }

  // ---- fused epilogue: gates + residual + dual store ----
  // C/D layout: col = lane&15, row = (lane>>4)*4 + q
#pragma unroll
  for (int jf = 0; jf < 2; ++jf) {
    int col = (nb << 6) + (wn << 5) + (jf << 4) + r15;
    float brc = b_ir[col] + b_hr[col];
    float bzc = b_iz[col] + b_hz[col];
    float bnc = b_in[col];
    float bhc = b_hn[col];
#pragma unroll
    for (int i = 0; i < 4; ++i) {
      int row0 = (mb << 8) + (wm << 6) + (i << 4) + (kb << 2);
#pragma unroll
      for (int q = 0; q < 4; ++q) {
        int row = row0 + q;
        float vr = acc_r[i][jf][q] + brc;
        float vz = acc_z[i][jf][q] + bzc;
        float vn = acc_n[i][jf][q] + bnc;
        float vh = acc_hn[i][jf][q] + bhc;
        float rg = __builtin_amdgcn_rcpf(1.f + __expf(-vr));
        float zg = __builtin_amdgcn_rcpf(1.f + __expf(-vz));
        float pre = vn + rg * vh;
        float ax = fabsf(pre);
        float e2 = __expf(-2.f * ax);
        float th = copysignf((1.f - e2) * __builtin_amdgcn_rcpf(1.f + e2), pre);
        float hp = hidf[((size_t)row << 10) + col];
        float h = (1.f - zg) * th + zg * hp;
        size_t o = ((size_t)row << 10) + col;
        out[o] = h;
        out[o + (size_t)BATCH * DD] = h;  // tuple (h, h)
      }
    }
  }
}

extern "C" void kernel_launch(void* const* d_in, const int* in_sizes, int n_in,
                              void* d_out, int out_size, void* d_ws, size_t ws_size,
                              hipStream_t stream) {
  (void)in_sizes; (void)n_in; (void)out_size; (void)ws_size;
  const float* inp = (const float*)d_in[0];
  const float* hid = (const float*)d_in[1];
  u16* ws_in  = (u16*)d_ws;
  u16* ws_hid = ws_in + (size_t)BATCH * DD;
  u16* ws_w   = ws_hid + (size_t)BATCH * DD;

  hipLaunchKernelGGL(cvt_all, dim3(4480), dim3(256), 0, stream,
                     (const float4*)inp, (const float4*)hid,
                     (const float4*)d_in[2], (const float4*)d_in[4],
                     (const float4*)d_in[6], (const float4*)d_in[8],
                     (const float4*)d_in[10], (const float4*)d_in[12],
                     (ushort4*)ws_in, (ushort4*)ws_hid, (ushort4*)ws_w);

  hipLaunchKernelGGL(gru_fused, dim3(2048), dim3(512), 0, stream,
                     ws_in, ws_hid, ws_w, hid,
                     (const float*)d_in[3], (const float*)d_in[5],
                     (const float*)d_in[7], (const float*)d_in[9],
                     (const float*)d_in[11], (const float*)d_in[13],
                     (float*)d_out);
}

// Round 6
// 561.190 us; speedup vs baseline: 1.1976x; 1.0298x over previous
//
#include <hip/hip_runtime.h>
#include <stdint.h>

#define DD 1024
#define BATCH 32768

typedef unsigned short u16;
typedef __attribute__((ext_vector_type(8))) __bf16 bf16x8;
typedef __attribute__((ext_vector_type(16))) float f32x16;
typedef __attribute__((ext_vector_type(4))) unsigned int u32x4;

__device__ __forceinline__ u16 f2bf(float x) {
  unsigned int u = __builtin_bit_cast(unsigned int, x);
  u = u + 0x7FFFu + ((u >> 16) & 1u);   // round-to-nearest-even
  return (u16)(u >> 16);
}

// One merged convert kernel: input (2048 blks), hidden (2048), 6 weights (64 each).
__global__ void cvt_all(const float4* __restrict__ in0, const float4* __restrict__ in1,
                        const float4* __restrict__ w0, const float4* __restrict__ w1,
                        const float4* __restrict__ w2, const float4* __restrict__ w3,
                        const float4* __restrict__ w4, const float4* __restrict__ w5,
                        ushort4* __restrict__ o0, ushort4* __restrict__ o1,
                        ushort4* __restrict__ ow) {
  int b = blockIdx.x;
  const float4* s; ushort4* d; int rel;
  if (b < 2048)      { s = in0; d = o0; rel = b; }
  else if (b < 4096) { s = in1; d = o1; rel = b - 2048; }
  else {
    int t = b - 4096; int g = t >> 6; rel = t & 63;
    s = (g == 0) ? w0 : (g == 1) ? w1 : (g == 2) ? w2 : (g == 3) ? w3 : (g == 4) ? w4 : w5;
    d = ow + (size_t)g * 262144;
  }
  int i0 = rel * 4096 + threadIdx.x;
#pragma unroll
  for (int j = 0; j < 16; ++j) {
    int i = i0 + j * 256;
    float4 v = s[i];
    ushort4 o;
    o.x = f2bf(v.x); o.y = f2bf(v.y); o.z = f2bf(v.z); o.w = f2bf(v.w);
    d[i] = o;
  }
}

// ---------------- fused GRU GEMM: R0 structure + 32x32x16 MFMA ----------------
// Tile: BM=128, BN=64, BK=64. 256 thr = 4 waves (2M x 2N), wave tile 64x32.
// LDS (u16): A_in[128][64] @0, A_h[128][64] @8192, W[g][64][64] @16384+g*4096.
// 80 KB -> 2 blocks/CU (the m114 implicit-overlap regime that gave R0's 885 TF).
// Swizzle (R0-verified, 0 conflicts): 128B rows, 8x 16B slots; natural k-slot k
// of row R stored at slot k ^ (R&7). 32x32 b128 reads: 64 lanes = rows l&31 x
// k-half l>>5 -> 8 lanes per 16B-position (uniform) -> conflict-free.
#define A_IN_U 0
#define A_H_U  8192
#define W_U(g) (16384 + (g) * 4096)

__device__ __forceinline__ bf16x8 ld8(const u16* p) {
  u32x4 v = *reinterpret_cast<const u32x4*>(p);
  return __builtin_bit_cast(bf16x8, v);
}

__device__ __forceinline__ f32x16 mfma32(bf16x8 a, bf16x8 b, f32x16 c) {
  return __builtin_amdgcn_mfma_f32_32x32x16_bf16(a, b, c, 0, 0, 0);
}

// Stage one 1KB chunk (8 rows x 128B); lane l -> row l>>3, slot l&7; global
// source pre-swizzled: fetches natural k-slot (l&7)^(l>>3) so linear LDS holds
// the swizzled layout (slot' = slot ^ (R&7)).
__device__ __forceinline__ void stage_chunk(const u16* grow, u16* ldsdst) {
  int l = threadIdx.x & 63;
  int r = l >> 3;
  int s = l & 7;
  const u16* src = grow + r * DD + ((s ^ r) << 3);
  __builtin_amdgcn_global_load_lds(
      (const __attribute__((address_space(1))) void*)src,
      (__attribute__((address_space(3))) void*)ldsdst, 16, 0, 0);
}

__global__ __launch_bounds__(256, 2) void gru_fused(
    const u16* __restrict__ ain, const u16* __restrict__ ah,
    const u16* __restrict__ wall, const float* __restrict__ hidf,
    const float* __restrict__ b_ir, const float* __restrict__ b_hr,
    const float* __restrict__ b_iz, const float* __restrict__ b_hz,
    const float* __restrict__ b_in, const float* __restrict__ b_hn,
    float* __restrict__ out) {
  __shared__ __align__(16) u16 lds[40960];  // 80 KB

  int bid = blockIdx.x;
  // L2-locality mapping (R4-verified: FETCH 1.18 -> 0.55 GB): XCD x owns mb
  // range [x*32, x*32+32); 16 consecutive blocks share one A-panel (L2-hot),
  // W slices come from L3.
  int x = bid & 7;
  int s = bid >> 3;              // 0..511
  int mb = (x << 5) | (s >> 4);  // 0..255
  int nb = s & 15;               // 0..15

  int tid = threadIdx.x;
  int wid = tid >> 6;
  int lane = tid & 63;
  int c31 = lane & 31;           // A-row / B-col within fragment
  int khalf = lane >> 5;         // k-half within 16-k step
  int wm = wid >> 1;             // 0..1
  int wn = wid & 1;              // 0..1

  f32x16 acc_r[2], acc_z[2], acc_n[2], acc_hn[2];
#pragma unroll
  for (int i = 0; i < 2; ++i) {
    acc_r[i] = (f32x16)0.f; acc_z[i] = (f32x16)0.f;
    acc_n[i] = (f32x16)0.f; acc_hn[i] = (f32x16)0.f;
  }

  const u16* ain_t = ain + ((size_t)(mb * 128) << 10);
  const u16* ah_t  = ah  + ((size_t)(mb * 128) << 10);
  const u16* w_t   = wall + ((size_t)(nb * 64) << 10);

  int possw = c31 & 7;  // read-side swizzle source (R&7 == c31&7 for all frags)

  for (int kt = 0; kt < 16; ++kt) {
    int kcol = kt << 6;
    __syncthreads();  // previous iter's compute done before overwrite
    // A tiles: 16 chunks each, 4 per wave
#pragma unroll
    for (int j = 0; j < 4; ++j) {
      int c = (j << 2) | wid;
      stage_chunk(ain_t + ((size_t)c << 13) + kcol, &lds[A_IN_U + c * 512]);
      stage_chunk(ah_t  + ((size_t)c << 13) + kcol, &lds[A_H_U  + c * 512]);
    }
    // W tiles: 8 chunks each, 2 per wave
#pragma unroll
    for (int g = 0; g < 6; ++g) {
      const u16* wg_t = w_t + ((size_t)g << 20) + kcol;
#pragma unroll
      for (int j = 0; j < 2; ++j) {
        int c = (j << 2) | wid;
        stage_chunk(wg_t + ((size_t)c << 13), &lds[W_U(g) + c * 512]);
      }
    }
    __syncthreads();  // drain -> LDS ready (2nd block on CU computes meanwhile)

#pragma unroll
    for (int ks = 0; ks < 4; ++ks) {
      int pos = (((ks << 1) | khalf) ^ possw) << 3;  // u16 offset of 16B slot
      bf16x8 afi[2], afh[2];
#pragma unroll
      for (int i = 0; i < 2; ++i) {
        int Rm = (wm << 6) + (i << 5) + c31;
        afi[i] = ld8(&lds[A_IN_U + Rm * 64 + pos]);
        afh[i] = ld8(&lds[A_H_U  + Rm * 64 + pos]);
      }
      int Rn = (wn << 5) + c31;
      const u16* W0 = &lds[W_U(0) + Rn * 64 + pos];
      bf16x8 bir = ld8(W0);
      bf16x8 bhr = ld8(W0 + 4096);
      bf16x8 biz = ld8(W0 + 8192);
      bf16x8 bhz = ld8(W0 + 12288);
      bf16x8 bin = ld8(W0 + 16384);
      bf16x8 bhn = ld8(W0 + 20480);
#pragma unroll
      for (int i = 0; i < 2; ++i) {
        acc_r[i]  = mfma32(afi[i], bir, acc_r[i]);
        acc_r[i]  = mfma32(afh[i], bhr, acc_r[i]);
        acc_z[i]  = mfma32(afi[i], biz, acc_z[i]);
        acc_z[i]  = mfma32(afh[i], bhz, acc_z[i]);
        acc_n[i]  = mfma32(afi[i], bin, acc_n[i]);
        acc_hn[i] = mfma32(afh[i], bhn, acc_hn[i]);
      }
    }
  }

  // ---- fused epilogue: gates + residual + dual store ----
  // 32x32 C/D layout (m74/m101): col = lane&31, row = (reg&3)+8*(reg>>2)+4*(lane>>5)
  int col = (nb << 6) + (wn << 5) + c31;
  float brc = b_ir[col] + b_hr[col];
  float bzc = b_iz[col] + b_hz[col];
  float bnc = b_in[col];
  float bhc = b_hn[col];
#pragma unroll
  for (int i = 0; i < 2; ++i) {
    int rbase = (mb << 7) + (wm << 6) + (i << 5) + (khalf << 2);
#pragma unroll
    for (int reg = 0; reg < 16; ++reg) {
      int row = rbase + (reg & 3) + ((reg >> 2) << 3);
      float vr = acc_r[i][reg] + brc;
      float vz = acc_z[i][reg] + bzc;
      float vn = acc_n[i][reg] + bnc;
      float vh = acc_hn[i][reg] + bhc;
      float rg = __builtin_amdgcn_rcpf(1.f + __expf(-vr));
      float zg = __builtin_amdgcn_rcpf(1.f + __expf(-vz));
      float pre = vn + rg * vh;
      float ax = fabsf(pre);
      float e2 = __expf(-2.f * ax);
      float th = copysignf((1.f - e2) * __builtin_amdgcn_rcpf(1.f + e2), pre);
      float hp = hidf[((size_t)row << 10) + col];
      float h = (1.f - zg) * th + zg * hp;
      size_t o = ((size_t)row << 10) + col;
      out[o] = h;
      out[o + (size_t)BATCH * DD] = h;  // tuple (h, h)
    }
  }
}

extern "C" void kernel_launch(void* const* d_in, const int* in_sizes, int n_in,
                              void* d_out, int out_size, void* d_ws, size_t ws_size,
                              hipStream_t stream) {
  (void)in_sizes; (void)n_in; (void)out_size; (void)ws_size;
  const float* inp = (const float*)d_in[0];
  const float* hid = (const float*)d_in[1];
  u16* ws_in  = (u16*)d_ws;
  u16* ws_hid = ws_in + (size_t)BATCH * DD;
  u16* ws_w   = ws_hid + (size_t)BATCH * DD;

  hipLaunchKernelGGL(cvt_all, dim3(4480), dim3(256), 0, stream,
                     (const float4*)inp, (const float4*)hid,
                     (const float4*)d_in[2], (const float4*)d_in[4],
                     (const float4*)d_in[6], (const float4*)d_in[8],
                     (const float4*)d_in[10], (const float4*)d_in[12],
                     (ushort4*)ws_in, (ushort4*)ws_hid, (ushort4*)ws_w);

  hipLaunchKernelGGL(gru_fused, dim3(4096), dim3(256), 0, stream,
                     ws_in, ws_hid, ws_w, hid,
                     (const float*)d_in[3], (const float*)d_in[5],
                     (const float*)d_in[7], (const float*)d_in[9],
                     (const float*)d_in[11], (const float*)d_in[13],
                     (float*)d_out);
}